// Round 1
// baseline (2068.288 us; speedup 1.0000x reference)
//
#include <hip/hip_runtime.h>

#define N_NODES 100000
#define N_EDGES 3200000
#define IN_DIM  512
#define HD_DIM  256
#define OUT_DIM 128

// ---------------- CSR build ----------------

__global__ void count_deg(const int* __restrict__ erow, int* __restrict__ cnt, int E) {
    int i = blockIdx.x * blockDim.x + threadIdx.x;
    if (i < E) atomicAdd(&cnt[erow[i]], 1);
}

// Single-block scan. deg_cursor holds degrees on entry; on exit holds row start
// offsets (used as fill cursors by scatter). rowptr gets the exclusive scan + total.
__global__ void scan_deg(int* deg_cursor, int* rowptr, int n) {
    __shared__ int sdata[1024];
    __shared__ int s_base;
    if (threadIdx.x == 0) s_base = 0;
    __syncthreads();
    int nc = (n + 1023) >> 10;
    for (int c = 0; c < nc; c++) {
        int i = (c << 10) + threadIdx.x;
        int v = (i < n) ? deg_cursor[i] : 0;
        sdata[threadIdx.x] = v;
        __syncthreads();
        for (int off = 1; off < 1024; off <<= 1) {
            int add = (threadIdx.x >= off) ? sdata[threadIdx.x - off] : 0;
            __syncthreads();
            sdata[threadIdx.x] += add;
            __syncthreads();
        }
        int incl = sdata[threadIdx.x];
        int base = s_base;
        int excl = base + incl - v;
        if (i < n) { rowptr[i] = excl; deg_cursor[i] = excl; }
        __syncthreads();
        if (threadIdx.x == 0) s_base = base + sdata[1023];
        __syncthreads();
    }
    if (threadIdx.x == 0) rowptr[n] = s_base;
}

__global__ void scatter_edges(const int* __restrict__ erow, const int* __restrict__ ecol,
                              const float* __restrict__ eval, int* cursor,
                              int* __restrict__ csr_col, float* __restrict__ csr_val, int E) {
    int i = blockIdx.x * blockDim.x + threadIdx.x;
    if (i < E) {
        int r = erow[i];
        int p = atomicAdd(&cursor[r], 1);
        csr_col[p] = ecol[i];
        csr_val[p] = eval[i];
    }
}

// ---------------- fp32 tiled GEMM: C[M,N] = (relu?)(A[M,K]) @ B[K,N] + bias ----------------
// BM=BN=64, BK=16, 256 threads, 4x4 microtile per thread.

template <bool RELU>
__global__ __launch_bounds__(256) void gemm_bias(const float* __restrict__ A,
                                                 const float* __restrict__ B,
                                                 const float* __restrict__ bias,
                                                 float* __restrict__ C,
                                                 int M, int N, int K) {
    __shared__ float As[16][68];  // As[k][m], padded stride 68 (272B, 16B-aligned)
    __shared__ float Bs[16][68];  // Bs[k][n]
    const int bm = blockIdx.x * 64;
    const int bn = blockIdx.y * 64;
    const int tid = threadIdx.x;
    const int tx = tid & 15;       // 0..15 -> 4 cols each
    const int ty = tid >> 4;       // 0..15 -> 4 rows each
    float acc[4][4] = {};

    const int ar = tid >> 2;        // 0..63 : A tile row
    const int ak = (tid & 3) * 4;   // 0,4,8,12 : A tile k start
    const int br = tid >> 4;        // 0..15 : B tile k row
    const int bc = (tid & 15) * 4;  // 0..60 : B tile col start

    for (int k0 = 0; k0 < K; k0 += 16) {
        float4 av;
        int arow = bm + ar;
        if (arow < M) {
            av = *(const float4*)&A[(long)arow * K + k0 + ak];
        } else {
            av = make_float4(0.f, 0.f, 0.f, 0.f);
        }
        if (RELU) {
            av.x = fmaxf(av.x, 0.f); av.y = fmaxf(av.y, 0.f);
            av.z = fmaxf(av.z, 0.f); av.w = fmaxf(av.w, 0.f);
        }
        As[ak + 0][ar] = av.x;
        As[ak + 1][ar] = av.y;
        As[ak + 2][ar] = av.z;
        As[ak + 3][ar] = av.w;

        float4 bv = *(const float4*)&B[(long)(k0 + br) * N + bn + bc];
        *(float4*)&Bs[br][bc] = bv;
        __syncthreads();

#pragma unroll
        for (int k = 0; k < 16; k++) {
            float4 a4 = *(const float4*)&As[k][ty * 4];
            float4 b4 = *(const float4*)&Bs[k][tx * 4];
            float a[4] = {a4.x, a4.y, a4.z, a4.w};
            float b[4] = {b4.x, b4.y, b4.z, b4.w};
#pragma unroll
            for (int i = 0; i < 4; i++)
#pragma unroll
                for (int j = 0; j < 4; j++) acc[i][j] += a[i] * b[j];
        }
        __syncthreads();
    }

    float4 bia = *(const float4*)&bias[bn + tx * 4];
#pragma unroll
    for (int i = 0; i < 4; i++) {
        int row = bm + ty * 4 + i;
        if (row < M) {
            float4 o;
            o.x = acc[i][0] + bia.x;
            o.y = acc[i][1] + bia.y;
            o.z = acc[i][2] + bia.z;
            o.w = acc[i][3] + bia.w;
            *(float4*)&C[(long)row * N + bn + tx * 4] = o;
        }
    }
}

// ---------------- CSR SPMM: H_out[r] = sum_e val * H_in[col], one wave per row ----------------

__global__ __launch_bounds__(256) void spmm_csr(const int* __restrict__ rowptr,
                                                const int* __restrict__ csr_col,
                                                const float* __restrict__ csr_val,
                                                const float* __restrict__ H_in,
                                                float* __restrict__ H_out) {
    const int wave = threadIdx.x >> 6;
    const int lane = threadIdx.x & 63;
    const int r = blockIdx.x * 4 + wave;
    if (r >= N_NODES) return;
    const int s = rowptr[r];
    const int e = rowptr[r + 1];
    float4 acc = make_float4(0.f, 0.f, 0.f, 0.f);
    for (int i = s; i < e; i++) {
        int c = csr_col[i];
        float v = csr_val[i];
        float4 hv = ((const float4*)(H_in + (long)c * HD_DIM))[lane];
        acc.x += v * hv.x;
        acc.y += v * hv.y;
        acc.z += v * hv.z;
        acc.w += v * hv.w;
    }
    ((float4*)(H_out + (long)r * HD_DIM))[lane] = acc;
}

// ---------------- launch ----------------

extern "C" void kernel_launch(void* const* d_in, const int* in_sizes, int n_in,
                              void* d_out, int out_size, void* d_ws, size_t ws_size,
                              hipStream_t stream) {
    const float* x    = (const float*)d_in[0];
    const int*   erow = (const int*)d_in[1];
    const int*   ecol = (const int*)d_in[2];
    const float* eval = (const float*)d_in[3];
    const float* W0   = (const float*)d_in[4];
    const float* b0   = (const float*)d_in[5];
    const float* W1   = (const float*)d_in[6];
    const float* b1   = (const float*)d_in[7];
    float* out = (float*)d_out;

    char* ws = (char*)d_ws;
    size_t off = 0;
    auto alloc = [&](size_t bytes) {
        void* p = ws + off;
        off += (bytes + 255) & ~(size_t)255;
        return p;
    };
    int*   rowptr  = (int*)alloc((N_NODES + 1) * sizeof(int));
    int*   cursor  = (int*)alloc(N_NODES * sizeof(int));
    int*   csr_col = (int*)alloc((size_t)N_EDGES * sizeof(int));
    float* csr_val = (float*)alloc((size_t)N_EDGES * sizeof(float));
    float* H0      = (float*)alloc((size_t)N_NODES * HD_DIM * sizeof(float));
    float* H1      = (float*)alloc((size_t)N_NODES * HD_DIM * sizeof(float));

    // CSR build (ws is re-poisoned to 0xAA before every launch -> must zero counts)
    hipMemsetAsync(cursor, 0, N_NODES * sizeof(int), stream);
    count_deg<<<(N_EDGES + 255) / 256, 256, 0, stream>>>(erow, cursor, N_EDGES);
    scan_deg<<<1, 1024, 0, stream>>>(cursor, rowptr, N_NODES);
    scatter_edges<<<(N_EDGES + 255) / 256, 256, 0, stream>>>(erow, ecol, eval, cursor,
                                                             csr_col, csr_val, N_EDGES);

    // H0 = x @ W0 + b0
    gemm_bias<false><<<dim3((N_NODES + 63) / 64, HD_DIM / 64), 256, 0, stream>>>(
        x, W0, b0, H0, N_NODES, HD_DIM, IN_DIM);

    // H1 = A @ H0 ; H0 <- A @ H1
    spmm_csr<<<(N_NODES + 3) / 4, 256, 0, stream>>>(rowptr, csr_col, csr_val, H0, H1);
    spmm_csr<<<(N_NODES + 3) / 4, 256, 0, stream>>>(rowptr, csr_col, csr_val, H1, H0);

    // out = relu(H2) @ W1 + b1
    gemm_bias<true><<<dim3((N_NODES + 63) / 64, OUT_DIM / 64), 256, 0, stream>>>(
        H0, W1, b1, out, N_NODES, OUT_DIM, HD_DIM);
}

// Round 2
// 1352.163 us; speedup vs baseline: 1.5296x; 1.5296x over previous
//
#include <hip/hip_runtime.h>

#define N_NODES 100000
#define N_EDGES 3200000
#define IN_DIM  512
#define HD_DIM  256
#define OUT_DIM 128

typedef short   short8  __attribute__((ext_vector_type(8)));
typedef unsigned short ushort8 __attribute__((ext_vector_type(8)));
typedef float   floatx4 __attribute__((ext_vector_type(4)));

__device__ __forceinline__ unsigned short f2bf(float f) {
    unsigned int u = __float_as_uint(f);
    u += 0x7fffu + ((u >> 16) & 1u);   // round-to-nearest-even
    return (unsigned short)(u >> 16);
}

// ---------------- CSR build ----------------

__global__ void count_deg(const int* __restrict__ erow, int* __restrict__ cnt, int E) {
    int i = blockIdx.x * blockDim.x + threadIdx.x;
    if (i < E) atomicAdd(&cnt[erow[i]], 1);
}

__global__ void scan_deg(int* deg_cursor, int* rowptr, int n) {
    __shared__ int sdata[1024];
    __shared__ int s_base;
    if (threadIdx.x == 0) s_base = 0;
    __syncthreads();
    int nc = (n + 1023) >> 10;
    for (int c = 0; c < nc; c++) {
        int i = (c << 10) + threadIdx.x;
        int v = (i < n) ? deg_cursor[i] : 0;
        sdata[threadIdx.x] = v;
        __syncthreads();
        for (int off = 1; off < 1024; off <<= 1) {
            int add = (threadIdx.x >= off) ? sdata[threadIdx.x - off] : 0;
            __syncthreads();
            sdata[threadIdx.x] += add;
            __syncthreads();
        }
        int incl = sdata[threadIdx.x];
        int base = s_base;
        int excl = base + incl - v;
        if (i < n) { rowptr[i] = excl; deg_cursor[i] = excl; }
        __syncthreads();
        if (threadIdx.x == 0) s_base = base + sdata[1023];
        __syncthreads();
    }
    if (threadIdx.x == 0) rowptr[n] = s_base;
}

__global__ void scatter_edges(const int* __restrict__ erow, const int* __restrict__ ecol,
                              const float* __restrict__ eval, int* cursor,
                              int* __restrict__ csr_col, float* __restrict__ csr_val, int E) {
    int i = blockIdx.x * blockDim.x + threadIdx.x;
    if (i < E) {
        int r = erow[i];
        int p = atomicAdd(&cursor[r], 1);
        csr_col[p] = ecol[i];
        csr_val[p] = eval[i];
    }
}

// ---------------- transpose + fp32->bf16 for weights: in[K][N] -> out[N][K] ----------------

__global__ void transpose_bf16(const float* __restrict__ in, unsigned short* __restrict__ out,
                               int K, int N) {
    int idx = blockIdx.x * blockDim.x + threadIdx.x;
    if (idx < K * N) {
        int k = idx / N, n = idx - k * N;
        out[n * K + k] = f2bf(in[idx]);
    }
}

// ---------------- MFMA bf16 GEMM: C[M,N] = (relu?)A[M,K] @ BT[N,K]^T + bias ----------------
// 128x128 block tile, 256 threads = 4 waves, each wave 64x64 (4x4 grid of 16x16x32 MFMA).
// LDS: As[128][40], Bs[128][40] bf16 (padded stride 40 -> conflict-free ds_read_b128).

template <bool A_FP32, bool RELU_A, bool OUT_BF16>
__global__ __launch_bounds__(256) void gemm_mfma(const void* __restrict__ Av,
                                                 const unsigned short* __restrict__ BT,
                                                 const float* __restrict__ bias,
                                                 void* __restrict__ Cv,
                                                 int M, int N, int K) {
    __shared__ unsigned short As[128 * 40];
    __shared__ unsigned short Bs[128 * 40];
    const int tid  = threadIdx.x;
    const int lane = tid & 63;
    const int wv   = tid >> 6;
    const int wm   = (wv >> 1) * 64;
    const int wn   = (wv & 1) * 64;
    const int mrow = lane & 15;
    const int q    = lane >> 4;
    const int bm   = blockIdx.x * 128;
    const int bn   = blockIdx.y * 128;

    floatx4 acc[4][4] = {};

    const int srow = tid >> 1;         // 0..127: tile row staged by this thread
    const int skh  = (tid & 1) * 16;   // k-offset 0 or 16

    for (int k0 = 0; k0 < K; k0 += 32) {
        // ---- stage A tile (128 x 32 bf16) ----
        {
            unsigned short tmp[16];
            const int grow = bm + srow;
            if (A_FP32) {
                const float* A = (const float*)Av;
                if (grow < M) {
                    const float4* p = (const float4*)&A[(long)grow * K + k0 + skh];
#pragma unroll
                    for (int v = 0; v < 4; v++) {
                        float4 f = p[v];
                        tmp[v * 4 + 0] = f2bf(f.x);
                        tmp[v * 4 + 1] = f2bf(f.y);
                        tmp[v * 4 + 2] = f2bf(f.z);
                        tmp[v * 4 + 3] = f2bf(f.w);
                    }
                } else {
#pragma unroll
                    for (int v = 0; v < 16; v++) tmp[v] = 0;
                }
            } else {
                const unsigned short* A = (const unsigned short*)Av;
                if (grow < M) {
                    const ushort8* p = (const ushort8*)&A[(long)grow * K + k0 + skh];
                    ushort8 u0 = p[0], u1 = p[1];
#pragma unroll
                    for (int v = 0; v < 8; v++) { tmp[v] = u0[v]; tmp[8 + v] = u1[v]; }
                    if (RELU_A) {
#pragma unroll
                        for (int v = 0; v < 16; v++)
                            if (tmp[v] & 0x8000u) tmp[v] = 0;
                    }
                } else {
#pragma unroll
                    for (int v = 0; v < 16; v++) tmp[v] = 0;
                }
            }
            ushort8* dst = (ushort8*)&As[srow * 40 + skh];
            ushort8 w0, w1;
#pragma unroll
            for (int v = 0; v < 8; v++) { w0[v] = tmp[v]; w1[v] = tmp[8 + v]; }
            dst[0] = w0;
            dst[1] = w1;
        }
        // ---- stage B tile (128 x 32 bf16) from BT[N][K] ----
        {
            const int gn = bn + srow;   // N is a multiple of 128 for both GEMMs
            const ushort8* p = (const ushort8*)&BT[(long)gn * K + k0 + skh];
            ushort8* dst = (ushort8*)&Bs[srow * 40 + skh];
            dst[0] = p[0];
            dst[1] = p[1];
        }
        __syncthreads();

        short8 af[4], bf[4];
#pragma unroll
        for (int i = 0; i < 4; i++)
            af[i] = *(const short8*)&As[(wm + i * 16 + mrow) * 40 + q * 8];
#pragma unroll
        for (int j = 0; j < 4; j++)
            bf[j] = *(const short8*)&Bs[(wn + j * 16 + mrow) * 40 + q * 8];
#pragma unroll
        for (int i = 0; i < 4; i++)
#pragma unroll
            for (int j = 0; j < 4; j++)
                acc[i][j] = __builtin_amdgcn_mfma_f32_16x16x32_bf16(af[i], bf[j], acc[i][j], 0, 0, 0);
        __syncthreads();
    }

    // ---- epilogue: C mapping col=lane&15, row=(lane>>4)*4+reg ----
#pragma unroll
    for (int i = 0; i < 4; i++) {
#pragma unroll
        for (int r = 0; r < 4; r++) {
            const int row = bm + wm + i * 16 + q * 4 + r;
            if (row < M) {
#pragma unroll
                for (int j = 0; j < 4; j++) {
                    const int col = bn + wn + j * 16 + mrow;
                    float v = acc[i][j][r] + bias[col];
                    if (OUT_BF16)
                        ((unsigned short*)Cv)[(long)row * N + col] = f2bf(v);
                    else
                        ((float*)Cv)[(long)row * N + col] = v;
                }
            }
        }
    }
}

// ---------------- CSR SPMM on bf16 H: one wave per row ----------------

__global__ __launch_bounds__(256) void spmm_bf16(const int* __restrict__ rowptr,
                                                 const int* __restrict__ csr_col,
                                                 const float* __restrict__ csr_val,
                                                 const unsigned short* __restrict__ Hin,
                                                 unsigned short* __restrict__ Hout) {
    const int wave = threadIdx.x >> 6;
    const int lane = threadIdx.x & 63;
    const int r = blockIdx.x * 4 + wave;
    if (r >= N_NODES) return;
    const int s = rowptr[r];
    const int e = rowptr[r + 1];
    const uint2* Hv = (const uint2*)Hin;  // 4 bf16 per uint2; row = 64 uint2
    float a0 = 0.f, a1 = 0.f, a2 = 0.f, a3 = 0.f;
    int i = s;
    for (; i + 1 < e; i += 2) {
        int   c0 = csr_col[i],     c1 = csr_col[i + 1];
        float v0 = csr_val[i],     v1 = csr_val[i + 1];
        uint2 h0 = Hv[(long)c0 * 64 + lane];
        uint2 h1 = Hv[(long)c1 * 64 + lane];
        a0 += v0 * __uint_as_float(h0.x << 16);
        a1 += v0 * __uint_as_float(h0.x & 0xffff0000u);
        a2 += v0 * __uint_as_float(h0.y << 16);
        a3 += v0 * __uint_as_float(h0.y & 0xffff0000u);
        a0 += v1 * __uint_as_float(h1.x << 16);
        a1 += v1 * __uint_as_float(h1.x & 0xffff0000u);
        a2 += v1 * __uint_as_float(h1.y << 16);
        a3 += v1 * __uint_as_float(h1.y & 0xffff0000u);
    }
    if (i < e) {
        int   c = csr_col[i];
        float v = csr_val[i];
        uint2 h = Hv[(long)c * 64 + lane];
        a0 += v * __uint_as_float(h.x << 16);
        a1 += v * __uint_as_float(h.x & 0xffff0000u);
        a2 += v * __uint_as_float(h.y << 16);
        a3 += v * __uint_as_float(h.y & 0xffff0000u);
    }
    uint2 o;
    o.x = (unsigned)f2bf(a0) | ((unsigned)f2bf(a1) << 16);
    o.y = (unsigned)f2bf(a2) | ((unsigned)f2bf(a3) << 16);
    ((uint2*)Hout)[(long)r * 64 + lane] = o;
}

// ---------------- launch ----------------

extern "C" void kernel_launch(void* const* d_in, const int* in_sizes, int n_in,
                              void* d_out, int out_size, void* d_ws, size_t ws_size,
                              hipStream_t stream) {
    const float* x    = (const float*)d_in[0];
    const int*   erow = (const int*)d_in[1];
    const int*   ecol = (const int*)d_in[2];
    const float* eval = (const float*)d_in[3];
    const float* W0   = (const float*)d_in[4];
    const float* b0   = (const float*)d_in[5];
    const float* W1   = (const float*)d_in[6];
    const float* b1   = (const float*)d_in[7];
    float* out = (float*)d_out;

    char* ws = (char*)d_ws;
    size_t off = 0;
    auto alloc = [&](size_t bytes) {
        void* p = ws + off;
        off += (bytes + 255) & ~(size_t)255;
        return p;
    };
    int*            rowptr  = (int*)alloc((N_NODES + 1) * sizeof(int));
    int*            cursor  = (int*)alloc(N_NODES * sizeof(int));
    int*            csr_col = (int*)alloc((size_t)N_EDGES * sizeof(int));
    float*          csr_val = (float*)alloc((size_t)N_EDGES * sizeof(float));
    unsigned short* W0T     = (unsigned short*)alloc((size_t)IN_DIM * HD_DIM * sizeof(unsigned short));
    unsigned short* W1T     = (unsigned short*)alloc((size_t)HD_DIM * OUT_DIM * sizeof(unsigned short));
    unsigned short* Ha      = (unsigned short*)alloc((size_t)N_NODES * HD_DIM * sizeof(unsigned short));
    unsigned short* Hb      = (unsigned short*)alloc((size_t)N_NODES * HD_DIM * sizeof(unsigned short));

    // CSR build (ws re-poisoned each launch -> zero the counters)
    hipMemsetAsync(cursor, 0, N_NODES * sizeof(int), stream);
    count_deg<<<(N_EDGES + 255) / 256, 256, 0, stream>>>(erow, cursor, N_EDGES);
    scan_deg<<<1, 1024, 0, stream>>>(cursor, rowptr, N_NODES);
    scatter_edges<<<(N_EDGES + 255) / 256, 256, 0, stream>>>(erow, ecol, eval, cursor,
                                                             csr_col, csr_val, N_EDGES);

    // weight transpose + convert
    transpose_bf16<<<(IN_DIM * HD_DIM + 255) / 256, 256, 0, stream>>>(W0, W0T, IN_DIM, HD_DIM);
    transpose_bf16<<<(HD_DIM * OUT_DIM + 255) / 256, 256, 0, stream>>>(W1, W1T, HD_DIM, OUT_DIM);

    // H0 = bf16(x @ W0 + b0)
    gemm_mfma<true, false, true><<<dim3((N_NODES + 127) / 128, HD_DIM / 128), 256, 0, stream>>>(
        x, W0T, b0, Ha, N_NODES, HD_DIM, IN_DIM);

    // H1 = A @ H0 ; H2 = A @ H1
    spmm_bf16<<<(N_NODES + 3) / 4, 256, 0, stream>>>(rowptr, csr_col, csr_val, Ha, Hb);
    spmm_bf16<<<(N_NODES + 3) / 4, 256, 0, stream>>>(rowptr, csr_col, csr_val, Hb, Ha);

    // out = relu(H2) @ W1 + b1  (fp32 out)
    gemm_mfma<false, true, false><<<dim3((N_NODES + 127) / 128, OUT_DIM / 128), 256, 0, stream>>>(
        Ha, W1T, b1, out, N_NODES, OUT_DIM, HD_DIM);
}

// Round 3
// 1209.422 us; speedup vs baseline: 1.7101x; 1.1180x over previous
//
#include <hip/hip_runtime.h>

#define N_NODES 100000
#define N_EDGES 3200000
#define IN_DIM  512
#define HD_DIM  256
#define OUT_DIM 128

typedef short   short8  __attribute__((ext_vector_type(8)));
typedef unsigned short ushort8 __attribute__((ext_vector_type(8)));
typedef float   floatx4 __attribute__((ext_vector_type(4)));

__device__ __forceinline__ unsigned short f2bf(float f) {
    unsigned int u = __float_as_uint(f);
    u += 0x7fffu + ((u >> 16) & 1u);   // round-to-nearest-even
    return (unsigned short)(u >> 16);
}

// ---------------- CSR build ----------------

__global__ void count_deg(const int* __restrict__ erow, int* __restrict__ cnt, int E) {
    int i = blockIdx.x * blockDim.x + threadIdx.x;
    if (i < E) atomicAdd(&cnt[erow[i]], 1);
}

// 3-stage multi-block exclusive scan of deg[n] -> rowptr[n+1] and cursor[n]
__global__ void scan_partial(const int* __restrict__ deg, int* __restrict__ bsum, int n) {
    __shared__ int sd[256];
    int i = blockIdx.x * 256 + threadIdx.x;
    sd[threadIdx.x] = (i < n) ? deg[i] : 0;
    __syncthreads();
    for (int off = 128; off > 0; off >>= 1) {
        if (threadIdx.x < off) sd[threadIdx.x] += sd[threadIdx.x + off];
        __syncthreads();
    }
    if (threadIdx.x == 0) bsum[blockIdx.x] = sd[0];
}

__global__ void scan_bsums(int* bsum, int nb) {  // one block, 512 threads, nb <= 512
    __shared__ int sd[512];
    int v = (threadIdx.x < nb) ? bsum[threadIdx.x] : 0;
    sd[threadIdx.x] = v;
    __syncthreads();
    for (int off = 1; off < 512; off <<= 1) {
        int add = (threadIdx.x >= off) ? sd[threadIdx.x - off] : 0;
        __syncthreads();
        sd[threadIdx.x] += add;
        __syncthreads();
    }
    if (threadIdx.x < nb) bsum[threadIdx.x] = sd[threadIdx.x] - v;  // exclusive
}

__global__ void scan_final(const int* __restrict__ deg, const int* __restrict__ bsum,
                           int* __restrict__ rowptr, int* __restrict__ cursor, int n) {
    __shared__ int sd[256];
    int i = blockIdx.x * 256 + threadIdx.x;
    int v = (i < n) ? deg[i] : 0;
    sd[threadIdx.x] = v;
    __syncthreads();
    for (int off = 1; off < 256; off <<= 1) {
        int add = (threadIdx.x >= off) ? sd[threadIdx.x - off] : 0;
        __syncthreads();
        sd[threadIdx.x] += add;
        __syncthreads();
    }
    int excl = bsum[blockIdx.x] + sd[threadIdx.x] - v;
    if (i < n) { rowptr[i] = excl; cursor[i] = excl; }
    if (i == 0) rowptr[n] = N_EDGES;
}

__global__ void scatter_edges(const int* __restrict__ erow, const int* __restrict__ ecol,
                              const float* __restrict__ eval, int* cursor,
                              uint2* __restrict__ csr, int E) {
    int i = blockIdx.x * blockDim.x + threadIdx.x;
    if (i < E) {
        int r = erow[i];
        int p = atomicAdd(&cursor[r], 1);
        csr[p] = make_uint2((unsigned)ecol[i], __float_as_uint(eval[i]));
    }
}

// ---------------- transpose + fp32->bf16 for weights: in[K][N] -> out[N][K] ----------------

__global__ void transpose_bf16(const float* __restrict__ in, unsigned short* __restrict__ out,
                               int K, int N) {
    int idx = blockIdx.x * blockDim.x + threadIdx.x;
    if (idx < K * N) {
        int k = idx / N, n = idx - k * N;
        out[n * K + k] = f2bf(in[idx]);
    }
}

// ---------------- MFMA bf16 GEMM: C[M,N] = (relu?)A[M,K] @ BT[N,K]^T + bias ----------------

template <bool A_FP32, bool RELU_A, bool OUT_BF16>
__global__ __launch_bounds__(256) void gemm_mfma(const void* __restrict__ Av,
                                                 const unsigned short* __restrict__ BT,
                                                 const float* __restrict__ bias,
                                                 void* __restrict__ Cv,
                                                 int M, int N, int K) {
    __shared__ unsigned short As[128 * 40];
    __shared__ unsigned short Bs[128 * 40];
    const int tid  = threadIdx.x;
    const int lane = tid & 63;
    const int wv   = tid >> 6;
    const int wm   = (wv >> 1) * 64;
    const int wn   = (wv & 1) * 64;
    const int mrow = lane & 15;
    const int q    = lane >> 4;
    const int bm   = blockIdx.x * 128;
    const int bn   = blockIdx.y * 128;

    floatx4 acc[4][4] = {};

    const int srow = tid >> 1;
    const int skh  = (tid & 1) * 16;

    for (int k0 = 0; k0 < K; k0 += 32) {
        {
            unsigned short tmp[16];
            const int grow = bm + srow;
            if (A_FP32) {
                const float* A = (const float*)Av;
                if (grow < M) {
                    const float4* p = (const float4*)&A[(long)grow * K + k0 + skh];
#pragma unroll
                    for (int v = 0; v < 4; v++) {
                        float4 f = p[v];
                        tmp[v * 4 + 0] = f2bf(f.x);
                        tmp[v * 4 + 1] = f2bf(f.y);
                        tmp[v * 4 + 2] = f2bf(f.z);
                        tmp[v * 4 + 3] = f2bf(f.w);
                    }
                } else {
#pragma unroll
                    for (int v = 0; v < 16; v++) tmp[v] = 0;
                }
            } else {
                const unsigned short* A = (const unsigned short*)Av;
                if (grow < M) {
                    const ushort8* p = (const ushort8*)&A[(long)grow * K + k0 + skh];
                    ushort8 u0 = p[0], u1 = p[1];
#pragma unroll
                    for (int v = 0; v < 8; v++) { tmp[v] = u0[v]; tmp[8 + v] = u1[v]; }
                    if (RELU_A) {
#pragma unroll
                        for (int v = 0; v < 16; v++)
                            if (tmp[v] & 0x8000u) tmp[v] = 0;
                    }
                } else {
#pragma unroll
                    for (int v = 0; v < 16; v++) tmp[v] = 0;
                }
            }
            ushort8* dst = (ushort8*)&As[srow * 40 + skh];
            ushort8 w0, w1;
#pragma unroll
            for (int v = 0; v < 8; v++) { w0[v] = tmp[v]; w1[v] = tmp[8 + v]; }
            dst[0] = w0;
            dst[1] = w1;
        }
        {
            const int gn = bn + srow;
            const ushort8* p = (const ushort8*)&BT[(long)gn * K + k0 + skh];
            ushort8* dst = (ushort8*)&Bs[srow * 40 + skh];
            dst[0] = p[0];
            dst[1] = p[1];
        }
        __syncthreads();

        short8 af[4], bf[4];
#pragma unroll
        for (int i = 0; i < 4; i++)
            af[i] = *(const short8*)&As[(wm + i * 16 + mrow) * 40 + q * 8];
#pragma unroll
        for (int j = 0; j < 4; j++)
            bf[j] = *(const short8*)&Bs[(wn + j * 16 + mrow) * 40 + q * 8];
#pragma unroll
        for (int i = 0; i < 4; i++)
#pragma unroll
            for (int j = 0; j < 4; j++)
                acc[i][j] = __builtin_amdgcn_mfma_f32_16x16x32_bf16(af[i], bf[j], acc[i][j], 0, 0, 0);
        __syncthreads();
    }

#pragma unroll
    for (int i = 0; i < 4; i++) {
#pragma unroll
        for (int r = 0; r < 4; r++) {
            const int row = bm + wm + i * 16 + q * 4 + r;
            if (row < M) {
#pragma unroll
                for (int j = 0; j < 4; j++) {
                    const int col = bn + wn + j * 16 + mrow;
                    float v = acc[i][j][r] + bias[col];
                    if (OUT_BF16)
                        ((unsigned short*)Cv)[(long)row * N + col] = f2bf(v);
                    else
                        ((float*)Cv)[(long)row * N + col] = v;
                }
            }
        }
    }
}

// ---------------- CSR SPMM on bf16 H: one wave per row, shfl-broadcast edges ----------------

__global__ __launch_bounds__(256) void spmm_bf16(const int* __restrict__ rowptr,
                                                 const uint2* __restrict__ edges,
                                                 const unsigned short* __restrict__ Hin,
                                                 unsigned short* __restrict__ Hout) {
    const int wave = threadIdx.x >> 6;
    const int lane = threadIdx.x & 63;
    const int r = blockIdx.x * 4 + wave;
    if (r >= N_NODES) return;
    const int s = rowptr[r];
    const int e = rowptr[r + 1];
    const uint2* __restrict__ Hv = (const uint2*)Hin;  // row = 64 uint2
    float a0 = 0.f, a1 = 0.f, a2 = 0.f, a3 = 0.f;

    for (int base = s; base < e; base += 64) {
        // one coalesced load of up to 64 (col,val) pairs; OOB lanes -> val 0
        int idx = base + lane;
        uint2 ev = (idx < e) ? edges[idx] : make_uint2(0u, 0u);
        int cnt = e - base;
        if (cnt > 64) cnt = 64;
        // unroll-8 groups; tail lanes broadcast (0, 0.0f) -> harmless gather of row 0
        for (int j0 = 0; j0 < cnt; j0 += 8) {
            uint2 h[8];
            float v[8];
#pragma unroll
            for (int u = 0; u < 8; u++) {
                int   c = __shfl((int)ev.x, j0 + u);
                v[u]    = __uint_as_float((unsigned)__shfl((int)ev.y, j0 + u));
                h[u]    = Hv[((unsigned)c << 6) + lane];
            }
#pragma unroll
            for (int u = 0; u < 8; u++) {
                a0 += v[u] * __uint_as_float(h[u].x << 16);
                a1 += v[u] * __uint_as_float(h[u].x & 0xffff0000u);
                a2 += v[u] * __uint_as_float(h[u].y << 16);
                a3 += v[u] * __uint_as_float(h[u].y & 0xffff0000u);
            }
        }
    }
    uint2 o;
    o.x = (unsigned)f2bf(a0) | ((unsigned)f2bf(a1) << 16);
    o.y = (unsigned)f2bf(a2) | ((unsigned)f2bf(a3) << 16);
    ((uint2*)Hout)[((unsigned)r << 6) + lane] = o;
}

// ---------------- launch ----------------

extern "C" void kernel_launch(void* const* d_in, const int* in_sizes, int n_in,
                              void* d_out, int out_size, void* d_ws, size_t ws_size,
                              hipStream_t stream) {
    const float* x    = (const float*)d_in[0];
    const int*   erow = (const int*)d_in[1];
    const int*   ecol = (const int*)d_in[2];
    const float* eval = (const float*)d_in[3];
    const float* W0   = (const float*)d_in[4];
    const float* b0   = (const float*)d_in[5];
    const float* W1   = (const float*)d_in[6];
    const float* b1   = (const float*)d_in[7];
    float* out = (float*)d_out;

    char* ws = (char*)d_ws;
    size_t off = 0;
    auto alloc = [&](size_t bytes) {
        void* p = ws + off;
        off += (bytes + 255) & ~(size_t)255;
        return p;
    };
    int*            rowptr  = (int*)alloc((N_NODES + 1) * sizeof(int));
    int*            deg     = (int*)alloc(N_NODES * sizeof(int));
    int*            cursor  = (int*)alloc(N_NODES * sizeof(int));
    int*            bsum    = (int*)alloc(512 * sizeof(int));
    uint2*          csr     = (uint2*)alloc((size_t)N_EDGES * sizeof(uint2));
    unsigned short* W0T     = (unsigned short*)alloc((size_t)IN_DIM * HD_DIM * sizeof(unsigned short));
    unsigned short* W1T     = (unsigned short*)alloc((size_t)HD_DIM * OUT_DIM * sizeof(unsigned short));
    unsigned short* Ha      = (unsigned short*)alloc((size_t)N_NODES * HD_DIM * sizeof(unsigned short));
    unsigned short* Hb      = (unsigned short*)alloc((size_t)N_NODES * HD_DIM * sizeof(unsigned short));

    const int nb = (N_NODES + 255) / 256;  // 391 <= 512

    // CSR build (ws re-poisoned each launch -> zero the counters)
    hipMemsetAsync(deg, 0, N_NODES * sizeof(int), stream);
    count_deg<<<(N_EDGES + 255) / 256, 256, 0, stream>>>(erow, deg, N_EDGES);
    scan_partial<<<nb, 256, 0, stream>>>(deg, bsum, N_NODES);
    scan_bsums<<<1, 512, 0, stream>>>(bsum, nb);
    scan_final<<<nb, 256, 0, stream>>>(deg, bsum, rowptr, cursor, N_NODES);
    scatter_edges<<<(N_EDGES + 255) / 256, 256, 0, stream>>>(erow, ecol, eval, cursor, csr, N_EDGES);

    // weight transpose + convert
    transpose_bf16<<<(IN_DIM * HD_DIM + 255) / 256, 256, 0, stream>>>(W0, W0T, IN_DIM, HD_DIM);
    transpose_bf16<<<(HD_DIM * OUT_DIM + 255) / 256, 256, 0, stream>>>(W1, W1T, HD_DIM, OUT_DIM);

    // H0 = bf16(x @ W0 + b0)
    gemm_mfma<true, false, true><<<dim3((N_NODES + 127) / 128, HD_DIM / 128), 256, 0, stream>>>(
        x, W0T, b0, Ha, N_NODES, HD_DIM, IN_DIM);

    // H1 = A @ H0 ; H2 = A @ H1
    spmm_bf16<<<(N_NODES + 3) / 4, 256, 0, stream>>>(rowptr, csr, Ha, Hb);
    spmm_bf16<<<(N_NODES + 3) / 4, 256, 0, stream>>>(rowptr, csr, Hb, Ha);

    // out = relu(H2) @ W1 + b1  (fp32 out)
    gemm_mfma<false, true, false><<<dim3((N_NODES + 127) / 128, OUT_DIM / 128), 256, 0, stream>>>(
        Ha, W1T, b1, out, N_NODES, OUT_DIM, HD_DIM);
}

// Round 4
// 936.638 us; speedup vs baseline: 2.2082x; 1.2912x over previous
//
#include <hip/hip_runtime.h>

#define N_NODES 100000
#define N_EDGES 3200000
#define IN_DIM  512
#define HD_DIM  256
#define OUT_DIM 128

#define NBINS 391          // bins of 256 rows: bin = row >> 8
#define EPT   16           // edges per thread in binning passes
#define EPB   (256 * EPT)  // edges per block = 4096

typedef short   short8  __attribute__((ext_vector_type(8)));
typedef unsigned short ushort8 __attribute__((ext_vector_type(8)));
typedef float   floatx4 __attribute__((ext_vector_type(4)));

__device__ __forceinline__ unsigned short f2bf(float f) {
    unsigned int u = __float_as_uint(f);
    u += 0x7fffu + ((u >> 16) & 1u);   // round-to-nearest-even
    return (unsigned short)(u >> 16);
}

// ---------------- CSR build: two-level binned counting sort ----------------

__global__ __launch_bounds__(256) void bin_count(const int* __restrict__ erow,
                                                 int* __restrict__ gbin, int E) {
    __shared__ int hist[NBINS];
    for (int i = threadIdx.x; i < NBINS; i += 256) hist[i] = 0;
    __syncthreads();
    long base = (long)blockIdx.x * EPB + threadIdx.x * EPT;
    if (base < E) {
        const int4* p = (const int4*)(erow + base);
#pragma unroll
        for (int v = 0; v < 4; v++) {
            int4 r4 = p[v];
            atomicAdd(&hist[r4.x >> 8], 1);
            atomicAdd(&hist[r4.y >> 8], 1);
            atomicAdd(&hist[r4.z >> 8], 1);
            atomicAdd(&hist[r4.w >> 8], 1);
        }
    }
    __syncthreads();
    for (int i = threadIdx.x; i < NBINS; i += 256)
        if (hist[i]) atomicAdd(&gbin[i], hist[i]);
}

__global__ void bin_scan(const int* __restrict__ gbin, int* __restrict__ bin_base,
                         int* __restrict__ gcursor, int* __restrict__ rowptr) {
    __shared__ int sd[512];
    int v = (threadIdx.x < NBINS) ? gbin[threadIdx.x] : 0;
    sd[threadIdx.x] = v;
    __syncthreads();
    for (int off = 1; off < 512; off <<= 1) {
        int add = (threadIdx.x >= off) ? sd[threadIdx.x - off] : 0;
        __syncthreads();
        sd[threadIdx.x] += add;
        __syncthreads();
    }
    if (threadIdx.x < NBINS) {
        int ex = sd[threadIdx.x] - v;
        bin_base[threadIdx.x] = ex;
        gcursor[threadIdx.x] = ex;
    }
    if (threadIdx.x == 0) { bin_base[NBINS] = N_EDGES; rowptr[N_NODES] = N_EDGES; }
}

// packed bin entry: x = (row_local << 20) | col, y = bits(val)
__global__ __launch_bounds__(256) void bin_scatter(const int* __restrict__ erow,
                                                   const int* __restrict__ ecol,
                                                   const float* __restrict__ eval,
                                                   int* __restrict__ gcursor,
                                                   uint2* __restrict__ binned, int E) {
    __shared__ int hist[NBINS];
    __shared__ int cur[NBINS];
    for (int i = threadIdx.x; i < NBINS; i += 256) hist[i] = 0;
    __syncthreads();
    long base = (long)blockIdx.x * EPB + threadIdx.x * EPT;
    int rows[EPT];
    const bool valid = base < E;   // chunks are all-in or all-out (E % 16 == 0)
    if (valid) {
        const int4* p = (const int4*)(erow + base);
#pragma unroll
        for (int v = 0; v < 4; v++) {
            int4 r = p[v];
            rows[4 * v + 0] = r.x; rows[4 * v + 1] = r.y;
            rows[4 * v + 2] = r.z; rows[4 * v + 3] = r.w;
        }
#pragma unroll
        for (int u = 0; u < EPT; u++) atomicAdd(&hist[rows[u] >> 8], 1);
    }
    __syncthreads();
    for (int i = threadIdx.x; i < NBINS; i += 256) {
        int h = hist[i];
        cur[i] = h ? atomicAdd(&gcursor[i], h) : 0;
    }
    __syncthreads();
    if (valid) {
        const int4*   pc = (const int4*)(ecol + base);
        const float4* pv = (const float4*)(eval + base);
#pragma unroll
        for (int v = 0; v < 4; v++) {
            int4 c4 = pc[v];
            float4 v4 = pv[v];
            int   cs[4] = {c4.x, c4.y, c4.z, c4.w};
            float vs[4] = {v4.x, v4.y, v4.z, v4.w};
#pragma unroll
            for (int u = 0; u < 4; u++) {
                int r = rows[4 * v + u];
                int pos = atomicAdd(&cur[r >> 8], 1);
                binned[pos] = make_uint2(((unsigned)(r & 255) << 20) | (unsigned)cs[u],
                                         __float_as_uint(vs[u]));
            }
        }
    }
}

// one workgroup per bin: local 256-row histogram -> rowptr + row-sorted CSR
__global__ __launch_bounds__(256) void bin_finalize(const int* __restrict__ bin_base,
                                                    const uint2* __restrict__ binned,
                                                    int* __restrict__ rowptr,
                                                    uint2* __restrict__ csr) {
    __shared__ int hist[256];
    __shared__ int cur[256];
    const int b = blockIdx.x;
    const int s = bin_base[b], e = bin_base[b + 1];
    const int t = threadIdx.x;
    hist[t] = 0;
    __syncthreads();
    for (int i = s + t; i < e; i += 256)
        atomicAdd(&hist[binned[i].x >> 20], 1);
    __syncthreads();
    int v = hist[t];
    for (int off = 1; off < 256; off <<= 1) {
        int add = (t >= off) ? hist[t - off] : 0;
        __syncthreads();
        hist[t] += add;
        __syncthreads();
    }
    int excl = hist[t] - v;
    int r = (b << 8) + t;
    if (r < N_NODES) rowptr[r] = s + excl;
    cur[t] = s + excl;
    __syncthreads();
    for (int i = s + t; i < e; i += 256) {
        uint2 ev = binned[i];
        int pos = atomicAdd(&cur[ev.x >> 20], 1);
        csr[pos] = make_uint2(ev.x & 0xFFFFFu, ev.y);
    }
}

// ---------------- transpose + fp32->bf16 for weights: in[K][N] -> out[N][K] ----------------

__global__ void transpose_bf16(const float* __restrict__ in, unsigned short* __restrict__ out,
                               int K, int N) {
    int idx = blockIdx.x * blockDim.x + threadIdx.x;
    if (idx < K * N) {
        int k = idx / N, n = idx - k * N;
        out[n * K + k] = f2bf(in[idx]);
    }
}

// ---------------- MFMA bf16 GEMM: C[M,N] = (relu?)A[M,K] @ BT[N,K]^T + bias ----------------

template <bool A_FP32, bool RELU_A, bool OUT_BF16>
__global__ __launch_bounds__(256) void gemm_mfma(const void* __restrict__ Av,
                                                 const unsigned short* __restrict__ BT,
                                                 const float* __restrict__ bias,
                                                 void* __restrict__ Cv,
                                                 int M, int N, int K) {
    __shared__ unsigned short As[128 * 40];
    __shared__ unsigned short Bs[128 * 40];
    const int tid  = threadIdx.x;
    const int lane = tid & 63;
    const int wv   = tid >> 6;
    const int wm   = (wv >> 1) * 64;
    const int wn   = (wv & 1) * 64;
    const int mrow = lane & 15;
    const int q    = lane >> 4;
    const int bm   = blockIdx.x * 128;
    const int bn   = blockIdx.y * 128;

    floatx4 acc[4][4] = {};

    const int srow = tid >> 1;
    const int skh  = (tid & 1) * 16;

    for (int k0 = 0; k0 < K; k0 += 32) {
        {
            unsigned short tmp[16];
            const int grow = bm + srow;
            if (A_FP32) {
                const float* A = (const float*)Av;
                if (grow < M) {
                    const float4* p = (const float4*)&A[(long)grow * K + k0 + skh];
#pragma unroll
                    for (int v = 0; v < 4; v++) {
                        float4 f = p[v];
                        tmp[v * 4 + 0] = f2bf(f.x);
                        tmp[v * 4 + 1] = f2bf(f.y);
                        tmp[v * 4 + 2] = f2bf(f.z);
                        tmp[v * 4 + 3] = f2bf(f.w);
                    }
                } else {
#pragma unroll
                    for (int v = 0; v < 16; v++) tmp[v] = 0;
                }
            } else {
                const unsigned short* A = (const unsigned short*)Av;
                if (grow < M) {
                    const ushort8* p = (const ushort8*)&A[(long)grow * K + k0 + skh];
                    ushort8 u0 = p[0], u1 = p[1];
#pragma unroll
                    for (int v = 0; v < 8; v++) { tmp[v] = u0[v]; tmp[8 + v] = u1[v]; }
                    if (RELU_A) {
#pragma unroll
                        for (int v = 0; v < 16; v++)
                            if (tmp[v] & 0x8000u) tmp[v] = 0;
                    }
                } else {
#pragma unroll
                    for (int v = 0; v < 16; v++) tmp[v] = 0;
                }
            }
            ushort8* dst = (ushort8*)&As[srow * 40 + skh];
            ushort8 w0, w1;
#pragma unroll
            for (int v = 0; v < 8; v++) { w0[v] = tmp[v]; w1[v] = tmp[8 + v]; }
            dst[0] = w0;
            dst[1] = w1;
        }
        {
            const int gn = bn + srow;
            const ushort8* p = (const ushort8*)&BT[(long)gn * K + k0 + skh];
            ushort8* dst = (ushort8*)&Bs[srow * 40 + skh];
            dst[0] = p[0];
            dst[1] = p[1];
        }
        __syncthreads();

        short8 af[4], bf[4];
#pragma unroll
        for (int i = 0; i < 4; i++)
            af[i] = *(const short8*)&As[(wm + i * 16 + mrow) * 40 + q * 8];
#pragma unroll
        for (int j = 0; j < 4; j++)
            bf[j] = *(const short8*)&Bs[(wn + j * 16 + mrow) * 40 + q * 8];
#pragma unroll
        for (int i = 0; i < 4; i++)
#pragma unroll
            for (int j = 0; j < 4; j++)
                acc[i][j] = __builtin_amdgcn_mfma_f32_16x16x32_bf16(af[i], bf[j], acc[i][j], 0, 0, 0);
        __syncthreads();
    }

#pragma unroll
    for (int i = 0; i < 4; i++) {
#pragma unroll
        for (int r = 0; r < 4; r++) {
            const int row = bm + wm + i * 16 + q * 4 + r;
            if (row < M) {
#pragma unroll
                for (int j = 0; j < 4; j++) {
                    const int col = bn + wn + j * 16 + mrow;
                    float v = acc[i][j][r] + bias[col];
                    if (OUT_BF16)
                        ((unsigned short*)Cv)[(long)row * N + col] = f2bf(v);
                    else
                        ((float*)Cv)[(long)row * N + col] = v;
                }
            }
        }
    }
}

// ---------------- CSR SPMM on bf16 H: one wave per row, shfl-broadcast edges ----------------

__global__ __launch_bounds__(256) void spmm_bf16(const int* __restrict__ rowptr,
                                                 const uint2* __restrict__ edges,
                                                 const unsigned short* __restrict__ Hin,
                                                 unsigned short* __restrict__ Hout) {
    const int wave = threadIdx.x >> 6;
    const int lane = threadIdx.x & 63;
    const int r = blockIdx.x * 4 + wave;
    if (r >= N_NODES) return;
    const int s = rowptr[r];
    const int e = rowptr[r + 1];
    const uint2* __restrict__ Hv = (const uint2*)Hin;  // row = 64 uint2
    float a0 = 0.f, a1 = 0.f, a2 = 0.f, a3 = 0.f;

    for (int base = s; base < e; base += 64) {
        int idx = base + lane;
        uint2 ev = (idx < e) ? edges[idx] : make_uint2(0u, 0u);
        int cnt = e - base;
        if (cnt > 64) cnt = 64;
        for (int j0 = 0; j0 < cnt; j0 += 8) {
            uint2 h[8];
            float v[8];
#pragma unroll
            for (int u = 0; u < 8; u++) {
                int   c = __shfl((int)ev.x, j0 + u);
                v[u]    = __uint_as_float((unsigned)__shfl((int)ev.y, j0 + u));
                h[u]    = Hv[((unsigned)c << 6) + lane];
            }
#pragma unroll
            for (int u = 0; u < 8; u++) {
                a0 += v[u] * __uint_as_float(h[u].x << 16);
                a1 += v[u] * __uint_as_float(h[u].x & 0xffff0000u);
                a2 += v[u] * __uint_as_float(h[u].y << 16);
                a3 += v[u] * __uint_as_float(h[u].y & 0xffff0000u);
            }
        }
    }
    uint2 o;
    o.x = (unsigned)f2bf(a0) | ((unsigned)f2bf(a1) << 16);
    o.y = (unsigned)f2bf(a2) | ((unsigned)f2bf(a3) << 16);
    ((uint2*)Hout)[((unsigned)r << 6) + lane] = o;
}

// ---------------- launch ----------------

extern "C" void kernel_launch(void* const* d_in, const int* in_sizes, int n_in,
                              void* d_out, int out_size, void* d_ws, size_t ws_size,
                              hipStream_t stream) {
    const float* x    = (const float*)d_in[0];
    const int*   erow = (const int*)d_in[1];
    const int*   ecol = (const int*)d_in[2];
    const float* eval = (const float*)d_in[3];
    const float* W0   = (const float*)d_in[4];
    const float* b0   = (const float*)d_in[5];
    const float* W1   = (const float*)d_in[6];
    const float* b1   = (const float*)d_in[7];
    float* out = (float*)d_out;

    char* ws = (char*)d_ws;
    size_t off = 0;
    auto alloc = [&](size_t bytes) {
        void* p = ws + off;
        off += (bytes + 255) & ~(size_t)255;
        return p;
    };
    int*            rowptr   = (int*)alloc((N_NODES + 1) * sizeof(int));
    int*            gbin     = (int*)alloc(NBINS * sizeof(int));
    int*            gcursor  = (int*)alloc(NBINS * sizeof(int));
    int*            bin_base = (int*)alloc((NBINS + 1) * sizeof(int));
    uint2*          binned   = (uint2*)alloc((size_t)N_EDGES * sizeof(uint2));
    uint2*          csr      = (uint2*)alloc((size_t)N_EDGES * sizeof(uint2));
    unsigned short* W0T      = (unsigned short*)alloc((size_t)IN_DIM * HD_DIM * sizeof(unsigned short));
    unsigned short* W1T      = (unsigned short*)alloc((size_t)HD_DIM * OUT_DIM * sizeof(unsigned short));
    unsigned short* Ha       = (unsigned short*)alloc((size_t)N_NODES * HD_DIM * sizeof(unsigned short));
    unsigned short* Hb       = (unsigned short*)alloc((size_t)N_NODES * HD_DIM * sizeof(unsigned short));

    const int nblk = (N_EDGES + EPB - 1) / EPB;  // 782

    // CSR build (ws re-poisoned each launch -> zero the counters)
    hipMemsetAsync(gbin, 0, NBINS * sizeof(int), stream);
    bin_count<<<nblk, 256, 0, stream>>>(erow, gbin, N_EDGES);
    bin_scan<<<1, 512, 0, stream>>>(gbin, bin_base, gcursor, rowptr);
    bin_scatter<<<nblk, 256, 0, stream>>>(erow, ecol, eval, gcursor, binned, N_EDGES);
    bin_finalize<<<NBINS, 256, 0, stream>>>(bin_base, binned, rowptr, csr);

    // weight transpose + convert
    transpose_bf16<<<(IN_DIM * HD_DIM + 255) / 256, 256, 0, stream>>>(W0, W0T, IN_DIM, HD_DIM);
    transpose_bf16<<<(HD_DIM * OUT_DIM + 255) / 256, 256, 0, stream>>>(W1, W1T, HD_DIM, OUT_DIM);

    // H0 = bf16(x @ W0 + b0)
    gemm_mfma<true, false, true><<<dim3((N_NODES + 127) / 128, HD_DIM / 128), 256, 0, stream>>>(
        x, W0T, b0, Ha, N_NODES, HD_DIM, IN_DIM);

    // H1 = A @ H0 ; H2 = A @ H1
    spmm_bf16<<<(N_NODES + 3) / 4, 256, 0, stream>>>(rowptr, csr, Ha, Hb);
    spmm_bf16<<<(N_NODES + 3) / 4, 256, 0, stream>>>(rowptr, csr, Hb, Ha);

    // out = relu(H2) @ W1 + b1  (fp32 out)
    gemm_mfma<false, true, false><<<dim3((N_NODES + 127) / 128, OUT_DIM / 128), 256, 0, stream>>>(
        Ha, W1T, b1, out, N_NODES, OUT_DIM, HD_DIM);
}